// Round 12
// baseline (30.904 us; speedup 1.0000x reference)
//
#include <hip/hip_runtime.h>
#include <math.h>

#define NB 32
#define NN 1024
#define NF 512

// ---------------- transpose W[NN][NF] -> Wt[NF][NN] ----------------
__global__ __launch_bounds__(256) void transpose_w_k(const float* __restrict__ W,
                                                     float* __restrict__ Wt) {
    __shared__ float tile[32][33];
    int n0 = blockIdx.x * 32;
    int f0 = blockIdx.y * 32;
    int tx = threadIdx.x & 31;
    int ty = threadIdx.x >> 5;  // 0..7
#pragma unroll
    for (int r = 0; r < 32; r += 8) {
        tile[ty + r][tx] = W[(n0 + ty + r) * NF + (f0 + tx)];
    }
    __syncthreads();
#pragma unroll
    for (int r = 0; r < 32; r += 8) {
        Wt[(f0 + ty + r) * NN + (n0 + tx)] = tile[tx][ty + r];
    }
}

// ---------------- DPP wave64 reductions (VALU-only, no DS pipe) ----------------
#define DPP_XOR1        0xB1   // quad_perm [1,0,3,2]
#define DPP_XOR2        0x4E   // quad_perm [2,3,0,1]
#define DPP_HALF_MIRROR 0x141
#define DPP_MIRROR      0x140
#define DPP_BCAST15     0x142
#define DPP_BCAST31     0x143

template <int CTRL>
__device__ __forceinline__ float dpp_mov(float v) {
    return __int_as_float(__builtin_amdgcn_update_dpp(
        0, __float_as_int(v), CTRL, 0xf, 0xf, true));
}

// wave-wide sum, wave-uniform result
__device__ __forceinline__ float wave_sum_u(float v) {
    v += dpp_mov<DPP_XOR1>(v);
    v += dpp_mov<DPP_XOR2>(v);
    v += dpp_mov<DPP_HALF_MIRROR>(v);
    v += dpp_mov<DPP_MIRROR>(v);
    v += dpp_mov<DPP_BCAST15>(v);
    v += dpp_mov<DPP_BCAST31>(v);
    return __int_as_float(__builtin_amdgcn_readlane(__float_as_int(v), 63));
}
// wave-wide max of NON-NEGATIVE values (bound_ctrl zeros are max-identity)
__device__ __forceinline__ float wave_max_u(float v) {
    v = fmaxf(v, dpp_mov<DPP_XOR1>(v));
    v = fmaxf(v, dpp_mov<DPP_XOR2>(v));
    v = fmaxf(v, dpp_mov<DPP_HALF_MIRROR>(v));
    v = fmaxf(v, dpp_mov<DPP_MIRROR>(v));
    v = fmaxf(v, dpp_mov<DPP_BCAST15>(v));
    v = fmaxf(v, dpp_mov<DPP_BCAST31>(v));
    return __int_as_float(__builtin_amdgcn_readlane(__float_as_int(v), 63));
}

__device__ __forceinline__ float fast_sqrt(float v) { return __builtin_amdgcn_sqrtf(v); }
__device__ __forceinline__ float fast_rcp(float v)  { return __builtin_amdgcn_rcpf(v); }

// s_sleep requires a CONSTANT immediate (R11 compile fail) -> constant-dispatch
__device__ __forceinline__ void sleep_by_wave(int w) {
    switch (w) {
        case 1: __builtin_amdgcn_s_sleep(1); break;
        case 2: __builtin_amdgcn_s_sleep(2); break;
        case 3: __builtin_amdgcn_s_sleep(3); break;
        case 4: __builtin_amdgcn_s_sleep(4); break;
        case 5: __builtin_amdgcn_s_sleep(5); break;
        case 6: __builtin_amdgcn_s_sleep(6); break;
        case 7: __builtin_amdgcn_s_sleep(7); break;
        default: break;
    }
}

// One wave per (output, side): solve F(t) = sum_j relu(m_j - t) = 1, m 16/lane.
// R10-validated numerics (floor 6.103516e-5): quad warm start + 5 hybrid sweeps
// (E>=1: accel 2(E-sqrt(E))/c, else Newton (E-1)/c), t clamped to [0,M] => c>=1.
// R12 delta: masked sum uses FOUR independent accumulators (dep-chain depth
// 16 -> 4+2; the 16-deep add chain was ~64 serial cy/sweep of pure latency).
// Internal names end in '_' (R8 shadowing lesson).
#define HYBRID5(MARR, SV, MV, RES_T)                                             \
    {                                                                            \
        float t_ = fminf(fmaxf(2.0f * (SV - fast_sqrt(SV)) * (1.0f/1024.0f),     \
                               0.0f), MV);                                       \
        _Pragma("unroll")                                                        \
        for (int s_ = 0; s_ < 5; ++s_) {                                         \
            float a0_ = 0.f, a1_ = 0.f, a2_ = 0.f, a3_ = 0.f;                    \
            int c_ = 0;                                                          \
            _Pragma("unroll")                                                    \
            for (int j_ = 0; j_ < 4; ++j_) {                                     \
                bool p0_ = (MARR[4*j_+0] >= t_);                                 \
                bool p1_ = (MARR[4*j_+1] >= t_);                                 \
                bool p2_ = (MARR[4*j_+2] >= t_);                                 \
                bool p3_ = (MARR[4*j_+3] >= t_);                                 \
                c_ += (int)__popcll(__ballot(p0_));                              \
                c_ += (int)__popcll(__ballot(p1_));                              \
                c_ += (int)__popcll(__ballot(p2_));                              \
                c_ += (int)__popcll(__ballot(p3_));                              \
                a0_ += p0_ ? MARR[4*j_+0] : 0.0f;                                \
                a1_ += p1_ ? MARR[4*j_+1] : 0.0f;                                \
                a2_ += p2_ ? MARR[4*j_+2] : 0.0f;                                \
                a3_ += p3_ ? MARR[4*j_+3] : 0.0f;                                \
            }                                                                    \
            float ss_ = wave_sum_u((a0_ + a1_) + (a2_ + a3_));                   \
            float fc_ = (float)c_;                                               \
            float E_ = ss_ - t_ * fc_;                                           \
            float d_ = (E_ >= 1.0f) ? 2.0f * (E_ - fast_sqrt(E_)) : (E_ - 1.0f); \
            t_ = fminf(fmaxf(t_ + d_ * fast_rcp(fc_), 0.0f), MV);                \
        }                                                                        \
        RES_T = t_;                                                              \
    }

// Cold path (S < 1: root u > 0): g(u) = 1024u + S + sum_{m<=u}(u - m) = 1.
#define COLD_POS(MARR, SV, RES_U)                                                \
    {                                                                            \
        float u_ = (1.0f - SV) * (1.0f/1024.0f);                                 \
        _Pragma("unroll 1")                                                      \
        for (int s_ = 0; s_ < 12; ++s_) {                                        \
            float s2_ = 0.f; int c2_ = 0;                                        \
            _Pragma("unroll")                                                    \
            for (int j_ = 0; j_ < 16; ++j_) {                                    \
                bool pr_ = (MARR[j_] <= u_);                                     \
                c2_ += (int)__popcll(__ballot(pr_));                             \
                s2_ += pr_ ? MARR[j_] : 0.0f;                                    \
            }                                                                    \
            s2_ = wave_sum_u(s2_);                                               \
            u_ = (1.0f - SV + s2_) * fast_rcp(1024.0f + (float)c2_);             \
        }                                                                        \
        RES_U = u_;                                                              \
    }

// Block = 512 threads = 8 waves: waves 0-3 = PLUS side of outputs (b,f0..f0+3),
// waves 4-7 = MINUS side. 32768 half-length waves total; combine via LDS.
// Per-wave s_sleep stagger breaks the lockstep convoy (8 identical waves
// starting the same cycle hit every sweep's serial tree+step phase together,
// stalling the whole SIMD at once; ~64cy/step skew decorrelates the phases).
__global__ __launch_bounds__(512, 8) void spike_main_k(const float* __restrict__ x,
                                                       const float* __restrict__ Wt,
                                                       float* __restrict__ out) {
    __shared__ float ures[8];

    int bid  = blockIdx.x;           // 0..4095
    int b    = bid >> 7;             // 0..31
    int fg   = bid & 127;            // 0..127
    int wave = threadIdx.x >> 6;     // 0..7
    int lane = threadIdx.x & 63;
    int side = wave >> 2;            // 0 = plus, 1 = minus
    int fi   = wave & 3;
    int f    = fg * 4 + fi;          // 0..511

    sleep_by_wave(wave);             // 0..7 x ~64cy stagger (one-time cost)

    const float4* x4 = reinterpret_cast<const float4*>(x + (size_t)b * NN);
    const float4* w4 = reinterpret_cast<const float4*>(Wt + (size_t)f * NN);

    const float h = side ? -0.5f : 0.5f;

    float m[16];
    float s0 = 0.f, s1 = 0.f, s2 = 0.f, s3 = 0.f;
    float x0 = 0.f, x1 = 0.f, x2 = 0.f, x3 = 0.f;
#pragma unroll
    for (int j = 0; j < 4; ++j) {
        float4 xv = x4[lane + 64 * j];
        float4 wv = w4[lane + 64 * j];
        float a;
        a = fabsf(fmaf(h, wv.x, xv.x)); m[4*j+0] = a; s0 += a; x0 = fmaxf(x0, a);
        a = fabsf(fmaf(h, wv.y, xv.y)); m[4*j+1] = a; s1 += a; x1 = fmaxf(x1, a);
        a = fabsf(fmaf(h, wv.z, xv.z)); m[4*j+2] = a; s2 += a; x2 = fmaxf(x2, a);
        a = fabsf(fmaf(h, wv.w, xv.w)); m[4*j+3] = a; s3 += a; x3 = fmaxf(x3, a);
    }

    // keep m opaque: prevents rematerialization (reload+fma+abs) inside sweeps
#pragma unroll
    for (int j = 0; j < 16; ++j) {
        asm volatile("" : "+v"(m[j]));
    }

    float S = wave_sum_u((s0 + s1) + (s2 + s3));
    float M = wave_max_u(fmaxf(fmaxf(x0, x1), fmaxf(x2, x3)));

    float u;
    if (S >= 1.0f) {          // root <= 0 (always, for this data)
        float t;
        HYBRID5(m, S, M, t);
        u = -t;
    } else {                  // general case: root > 0
        COLD_POS(m, S, u);
    }

    if (lane == 0) ures[wave] = u;
    __syncthreads();

    if (wave < 4 && lane == 0) {
        // out = relu(u_plus - u_minus)
        out[(size_t)b * NF + f] = fmaxf(ures[wave] - ures[wave + 4], 0.0f);
    }
}

extern "C" void kernel_launch(void* const* d_in, const int* in_sizes, int n_in,
                              void* d_out, int out_size, void* d_ws, size_t ws_size,
                              hipStream_t stream) {
    const float* x = (const float*)d_in[0];   // 32 x 1024
    const float* W = (const float*)d_in[1];   // 1024 x 512
    float* out = (float*)d_out;               // 32 x 512
    float* Wt = (float*)d_ws;                 // needs 2MB scratch

    dim3 g(NN / 32, NF / 32);  // 32 x 16
    transpose_w_k<<<g, 256, 0, stream>>>(W, Wt);
    spike_main_k<<<4096, 512, 0, stream>>>(x, Wt, out);
}

// Round 13
// 28.876 us; speedup vs baseline: 1.0702x; 1.0702x over previous
//
#include <hip/hip_runtime.h>
#include <math.h>

#define NB 32
#define NN 1024
#define NF 512

// ---------------- transpose W[NN][NF] -> Wt[NF][NN] ----------------
__global__ __launch_bounds__(256) void transpose_w_k(const float* __restrict__ W,
                                                     float* __restrict__ Wt) {
    __shared__ float tile[32][33];
    int n0 = blockIdx.x * 32;
    int f0 = blockIdx.y * 32;
    int tx = threadIdx.x & 31;
    int ty = threadIdx.x >> 5;  // 0..7
#pragma unroll
    for (int r = 0; r < 32; r += 8) {
        tile[ty + r][tx] = W[(n0 + ty + r) * NF + (f0 + tx)];
    }
    __syncthreads();
#pragma unroll
    for (int r = 0; r < 32; r += 8) {
        Wt[(f0 + ty + r) * NN + (n0 + tx)] = tile[tx][ty + r];
    }
}

// ---------------- DPP wave64 reductions (VALU-only, no DS pipe) ----------------
#define DPP_XOR1        0xB1   // quad_perm [1,0,3,2]
#define DPP_XOR2        0x4E   // quad_perm [2,3,0,1]
#define DPP_HALF_MIRROR 0x141
#define DPP_MIRROR      0x140
#define DPP_BCAST15     0x142
#define DPP_BCAST31     0x143

template <int CTRL>
__device__ __forceinline__ float dpp_mov(float v) {
    return __int_as_float(__builtin_amdgcn_update_dpp(
        0, __float_as_int(v), CTRL, 0xf, 0xf, true));
}

// wave-wide sum, wave-uniform result
__device__ __forceinline__ float wave_sum_u(float v) {
    v += dpp_mov<DPP_XOR1>(v);
    v += dpp_mov<DPP_XOR2>(v);
    v += dpp_mov<DPP_HALF_MIRROR>(v);
    v += dpp_mov<DPP_MIRROR>(v);
    v += dpp_mov<DPP_BCAST15>(v);
    v += dpp_mov<DPP_BCAST31>(v);
    return __int_as_float(__builtin_amdgcn_readlane(__float_as_int(v), 63));
}
// wave-wide max of NON-NEGATIVE values (bound_ctrl zeros are max-identity)
__device__ __forceinline__ float wave_max_u(float v) {
    v = fmaxf(v, dpp_mov<DPP_XOR1>(v));
    v = fmaxf(v, dpp_mov<DPP_XOR2>(v));
    v = fmaxf(v, dpp_mov<DPP_HALF_MIRROR>(v));
    v = fmaxf(v, dpp_mov<DPP_MIRROR>(v));
    v = fmaxf(v, dpp_mov<DPP_BCAST15>(v));
    v = fmaxf(v, dpp_mov<DPP_BCAST31>(v));
    return __int_as_float(__builtin_amdgcn_readlane(__float_as_int(v), 63));
}

__device__ __forceinline__ float fast_sqrt(float v) { return __builtin_amdgcn_sqrtf(v); }
__device__ __forceinline__ float fast_rcp(float v)  { return __builtin_amdgcn_rcpf(v); }

// One wave per (output, side): wave solves F(t) = sum_j relu(m_j - t) = 1 with
// m = |x + sgn*0.5*W| held 16/lane. R10-validated numerics (floor 6.103516e-5
// at 28.8us): quad-model warm start + 5 hybrid sweeps (E>=1: accelerated
// 2(E-sqrt(E))/c, else Newton (E-1)/c), clamped t in [0,M] so count>=1.
// All macro-internal names end in '_' (R8 shadowing lesson).
// NOTE (R12): 4-way accumulator ILP split + per-wave s_sleep stagger measured
// -2.1us WORSE than this plain version; reverted.
#define HYBRID5(MARR, SV, MV, RES_T)                                             \
    {                                                                            \
        float t_ = fminf(fmaxf(2.0f * (SV - fast_sqrt(SV)) * (1.0f/1024.0f),     \
                               0.0f), MV);                                       \
        _Pragma("unroll")                                                        \
        for (int s_ = 0; s_ < 5; ++s_) {                                         \
            float ss_ = 0.f; int c_ = 0;                                         \
            _Pragma("unroll")                                                    \
            for (int j_ = 0; j_ < 16; ++j_) {                                    \
                bool pr_ = (MARR[j_] >= t_);                                     \
                c_ += (int)__popcll(__ballot(pr_));                              \
                ss_ += pr_ ? MARR[j_] : 0.0f;                                    \
            }                                                                    \
            ss_ = wave_sum_u(ss_);                                               \
            float fc_ = (float)c_;                                               \
            float E_ = ss_ - t_ * fc_;                                           \
            float d_ = (E_ >= 1.0f) ? 2.0f * (E_ - fast_sqrt(E_)) : (E_ - 1.0f); \
            t_ = fminf(fmaxf(t_ + d_ * fast_rcp(fc_), 0.0f), MV);                \
        }                                                                        \
        RES_T = t_;                                                              \
    }

// Cold path (S < 1: root u > 0): g(u) = 1024u + S + sum_{m<=u}(u - m) = 1.
#define COLD_POS(MARR, SV, RES_U)                                                \
    {                                                                            \
        float u_ = (1.0f - SV) * (1.0f/1024.0f);                                 \
        _Pragma("unroll 1")                                                      \
        for (int s_ = 0; s_ < 12; ++s_) {                                        \
            float s2_ = 0.f; int c2_ = 0;                                        \
            _Pragma("unroll")                                                    \
            for (int j_ = 0; j_ < 16; ++j_) {                                    \
                bool pr_ = (MARR[j_] <= u_);                                     \
                c2_ += (int)__popcll(__ballot(pr_));                             \
                s2_ += pr_ ? MARR[j_] : 0.0f;                                    \
            }                                                                    \
            s2_ = wave_sum_u(s2_);                                               \
            u_ = (1.0f - SV + s2_) * fast_rcp(1024.0f + (float)c2_);             \
        }                                                                        \
        RES_U = u_;                                                              \
    }

// Block = 512 threads = 8 waves: waves 0-3 solve the PLUS side of outputs
// (b, f0..f0+3), waves 4-7 the MINUS side of the same outputs. Each wave's
// work is HALF of R7's (one side), doubling wave count to 32768 for better
// latency-bubble overlap; combine via 1 LDS word/wave + one barrier.
__global__ __launch_bounds__(512, 8) void spike_main_k(const float* __restrict__ x,
                                                       const float* __restrict__ Wt,
                                                       float* __restrict__ out) {
    __shared__ float ures[8];

    int bid  = blockIdx.x;           // 0..4095
    int b    = bid >> 7;             // 0..31
    int fg   = bid & 127;            // 0..127
    int wave = threadIdx.x >> 6;     // 0..7
    int lane = threadIdx.x & 63;
    int side = wave >> 2;            // 0 = plus, 1 = minus
    int fi   = wave & 3;
    int f    = fg * 4 + fi;          // 0..511

    const float4* x4 = reinterpret_cast<const float4*>(x + (size_t)b * NN);
    const float4* w4 = reinterpret_cast<const float4*>(Wt + (size_t)f * NN);

    const float h = side ? -0.5f : 0.5f;

    float m[16];
    float s0 = 0.f, x0 = 0.f;
#pragma unroll
    for (int j = 0; j < 4; ++j) {
        float4 xv = x4[lane + 64 * j];
        float4 wv = w4[lane + 64 * j];
        float a;
        a = fabsf(fmaf(h, wv.x, xv.x)); m[4*j+0] = a; s0 += a; x0 = fmaxf(x0, a);
        a = fabsf(fmaf(h, wv.y, xv.y)); m[4*j+1] = a; s0 += a; x0 = fmaxf(x0, a);
        a = fabsf(fmaf(h, wv.z, xv.z)); m[4*j+2] = a; s0 += a; x0 = fmaxf(x0, a);
        a = fabsf(fmaf(h, wv.w, xv.w)); m[4*j+3] = a; s0 += a; x0 = fmaxf(x0, a);
    }

    // keep m opaque: prevents rematerialization (reload+fma+abs) inside sweeps
#pragma unroll
    for (int j = 0; j < 16; ++j) {
        asm volatile("" : "+v"(m[j]));
    }

    float S = wave_sum_u(s0);
    float M = wave_max_u(x0);

    float u;
    if (S >= 1.0f) {          // root <= 0 (always, for this data)
        float t;
        HYBRID5(m, S, M, t);
        u = -t;
    } else {                  // general case: root > 0
        COLD_POS(m, S, u);
    }

    if (lane == 0) ures[wave] = u;
    __syncthreads();

    if (wave < 4 && lane == 0) {
        // out = relu(u_plus - u_minus)
        out[(size_t)b * NF + f] = fmaxf(ures[wave] - ures[wave + 4], 0.0f);
    }
}

extern "C" void kernel_launch(void* const* d_in, const int* in_sizes, int n_in,
                              void* d_out, int out_size, void* d_ws, size_t ws_size,
                              hipStream_t stream) {
    const float* x = (const float*)d_in[0];   // 32 x 1024
    const float* W = (const float*)d_in[1];   // 1024 x 512
    float* out = (float*)d_out;               // 32 x 512
    float* Wt = (float*)d_ws;                 // needs 2MB scratch

    dim3 g(NN / 32, NF / 32);  // 32 x 16
    transpose_w_k<<<g, 256, 0, stream>>>(W, Wt);
    spike_main_k<<<4096, 512, 0, stream>>>(x, Wt, out);
}